// Round 19
// baseline (358.898 us; speedup 1.0000x reference)
//
#include <hip/hip_runtime.h>
#include <hip/hip_bf16.h>
#include <hip/hip_fp16.h>
#include <math.h>

// fp16 helpers — message/activation tables are fp16; packed half2 math keeps the
// gather inner loop at 4 VALU per uint4 (round-14).
__device__ __forceinline__ unsigned h2u(__half2 h) { return *reinterpret_cast<unsigned*>(&h); }
__device__ __forceinline__ __half2 u2h(unsigned u) { return *reinterpret_cast<__half2*>(&u); }
__device__ __forceinline__ __half2 shfl_h2(__half2 h, int off) {
  int v = __shfl_xor((int)h2u(h), off);
  unsigned uv = (unsigned)v;
  return u2h(uv);
}

// ---------------- graph build: bucket-sort CSR, no per-node atomics ----------------
// ROUND-17 LESSON: no block-barrier fusion of agg+gemm (kills wave load balance).
// ROUND-18 LESSON: build kernels were launch-width-starved — bin_pass1 had 293
// blocks (1.1/CU, latency-bound). P1E 16->4 and 128-node buckets (391->782
// pass2 blocks) restore occupancy.

#define P1E 4    // edges per thread in pass 1 (was 16: only 293 blocks)
#define BKB 7    // bucket = dst >> 7 (128 nodes)
#define BKM 127
#define NBK 800  // max buckets (100k/128 = 782)

// fused: bucket histogram (blocks < fillBlocks) + layer-1 GEMM (rest).
__global__ __launch_bounds__(256) void hist_gemm1(const int* __restrict__ dst,
                                                  int* __restrict__ bcnt, int e,
                                                  int fillBlocks,
                                                  const float* __restrict__ H,
                                                  const float* __restrict__ W,
                                                  unsigned short* __restrict__ T, int n) {
  __shared__ int lcnt[NBK];
  __shared__ float Ws[64 * 64];
  if ((int)blockIdx.x < fillBlocks) {
    for (int i = threadIdx.x; i < NBK; i += 256) lcnt[i] = 0;
    __syncthreads();
    int base = blockIdx.x * (256 * P1E);
#pragma unroll
    for (int r = 0; r < P1E; ++r) {
      int i = base + r * 256 + threadIdx.x;
      if (i < e) atomicAdd(&lcnt[dst[i] >> BKB], 1);
    }
    __syncthreads();
    for (int b = threadIdx.x; b < NBK; b += 256)
      if (lcnt[b]) atomicAdd(&bcnt[b], lcnt[b]);
    return;
  }
  // gemm1: IN=64 f32, OUT=64, UNSCALED (layer-1 agg applies dinv per edge)
  for (int idx = threadIdx.x; idx < 64 * 64 / 4; idx += 256)
    reinterpret_cast<float4*>(Ws)[idx] = reinterpret_cast<const float4*>(W)[idx];
  __syncthreads();
  int bid = blockIdx.x - fillBlocks;
  int tx = threadIdx.x % 16;
  int ty = threadIdx.x / 16;
  int j0 = tx * 4;
  int n0 = bid * 32 + ty * 2;
  const float* h0p = H + (size_t)min(n0 + 0, n - 1) * 64;
  const float* h1p = H + (size_t)min(n0 + 1, n - 1) * 64;
  float4 acc0 = {0,0,0,0}, acc1 = {0,0,0,0};
#pragma unroll 2
  for (int k = 0; k < 64; k += 4) {
    float4 ha = *reinterpret_cast<const float4*>(h0p + k);
    float4 hb = *reinterpret_cast<const float4*>(h1p + k);
    float4 w0 = *reinterpret_cast<const float4*>(&Ws[(k + 0) * 64 + j0]);
    float4 w1 = *reinterpret_cast<const float4*>(&Ws[(k + 1) * 64 + j0]);
    float4 w2 = *reinterpret_cast<const float4*>(&Ws[(k + 2) * 64 + j0]);
    float4 w3 = *reinterpret_cast<const float4*>(&Ws[(k + 3) * 64 + j0]);
#define A4(A, HV)                                                                \
    A.x = fmaf(HV.x, w0.x, A.x); A.y = fmaf(HV.x, w0.y, A.y);                    \
    A.z = fmaf(HV.x, w0.z, A.z); A.w = fmaf(HV.x, w0.w, A.w);                    \
    A.x = fmaf(HV.y, w1.x, A.x); A.y = fmaf(HV.y, w1.y, A.y);                    \
    A.z = fmaf(HV.y, w1.z, A.z); A.w = fmaf(HV.y, w1.w, A.w);                    \
    A.x = fmaf(HV.z, w2.x, A.x); A.y = fmaf(HV.z, w2.y, A.y);                    \
    A.z = fmaf(HV.z, w2.z, A.z); A.w = fmaf(HV.z, w2.w, A.w);                    \
    A.x = fmaf(HV.w, w3.x, A.x); A.y = fmaf(HV.w, w3.y, A.y);                    \
    A.z = fmaf(HV.w, w3.z, A.z); A.w = fmaf(HV.w, w3.w, A.w);
    A4(acc0, ha) A4(acc1, hb)
#undef A4
  }
  float4 av[2] = {acc0, acc1};
#pragma unroll
  for (int i = 0; i < 2; ++i) {
    int node = n0 + i;
    if (node < n) {
      uint2 st;
      st.x = h2u(__floats2half2_rn(av[i].x, av[i].y));
      st.y = h2u(__floats2half2_rn(av[i].z, av[i].w));
      *reinterpret_cast<uint2*>(T + (size_t)node * 64 + j0) = st;
    }
  }
}

__global__ __launch_bounds__(1024) void bucket_scan(const int* __restrict__ bcnt,
                                                    int* __restrict__ bucket_base,
                                                    int* __restrict__ gcursor,
                                                    int nb, int e) {
  __shared__ int s[1024];
  int v = (threadIdx.x < (unsigned)nb) ? bcnt[threadIdx.x] : 0;
  s[threadIdx.x] = v;
  __syncthreads();
  for (int off = 1; off < 1024; off <<= 1) {
    int t = (threadIdx.x >= (unsigned)off) ? s[threadIdx.x - off] : 0;
    __syncthreads();
    s[threadIdx.x] += t;
    __syncthreads();
  }
  if (threadIdx.x < (unsigned)nb) {
    int excl = s[threadIdx.x] - v;
    bucket_base[threadIdx.x] = excl;
    gcursor[threadIdx.x] = excl;
  }
  if (threadIdx.x == 0) bucket_base[nb] = e;
}

// pass 1 — bin edges into per-bucket stream regions; record = (src<<7)|(dst&127)
__global__ __launch_bounds__(256) void bin_pass1(const int* __restrict__ src,
                                                 const int* __restrict__ dst,
                                                 int* __restrict__ gcursor,
                                                 unsigned* __restrict__ stream, int e) {
  __shared__ int lcnt[NBK], gbase[NBK];
  for (int i = threadIdx.x; i < NBK; i += 256) lcnt[i] = 0;
  __syncthreads();
  int base = blockIdx.x * (256 * P1E);
  int rankr[P1E];
#pragma unroll
  for (int r = 0; r < P1E; ++r) {
    int i = base + r * 256 + threadIdx.x;
    rankr[r] = (i < e) ? atomicAdd(&lcnt[dst[i] >> BKB], 1) : 0;
  }
  __syncthreads();
  for (int bkt = threadIdx.x; bkt < NBK; bkt += 256)
    gbase[bkt] = lcnt[bkt] ? atomicAdd(&gcursor[bkt], lcnt[bkt]) : 0;
  __syncthreads();
#pragma unroll
  for (int r = 0; r < P1E; ++r) {
    int i = base + r * 256 + threadIdx.x;
    if (i < e) {
      int d = dst[i];
      stream[gbase[d >> BKB] + rankr[r]] = ((unsigned)src[i] << BKB) | (unsigned)(d & BKM);
    }
  }
}

// pass 2 — per-bucket (128 nodes): derive per-node counts (LDS), scan ->
// row_start + cnt (coalesced), then LDS scatter -> coalesced csr_src.

#define LCAP 4096  // bucket span capacity (mean 1536, +65 sigma margin)

__global__ __launch_bounds__(256) void bin_pass2(const unsigned* __restrict__ stream,
                                                 const int* __restrict__ bucket_base,
                                                 int* __restrict__ row_start,
                                                 int* __restrict__ cnt,
                                                 int* __restrict__ csr_src,
                                                 int n, int e) {
  __shared__ int lcnt[128];
  __shared__ int lscan[128];
  __shared__ int lcur[128];
  __shared__ int lbuf[LCAP];
  int node_lo = blockIdx.x << BKB;
  int nn = min(128, n - node_lo);
  int lo = bucket_base[blockIdx.x];
  int hi = bucket_base[blockIdx.x + 1];
  int sz = hi - lo;
  if (threadIdx.x < 128) lcnt[threadIdx.x] = 0;
  __syncthreads();
  for (int j = threadIdx.x; j < sz; j += 256)
    atomicAdd(&lcnt[stream[lo + j] & BKM], 1);
  __syncthreads();
  int v = 0;
  if (threadIdx.x < 128) {
    v = lcnt[threadIdx.x];
    lscan[threadIdx.x] = v;
  }
  __syncthreads();
  for (int off = 1; off < 128; off <<= 1) {
    int t = 0;
    if (threadIdx.x < 128 && threadIdx.x >= (unsigned)off) t = lscan[threadIdx.x - off];
    __syncthreads();
    if (threadIdx.x < 128) lscan[threadIdx.x] += t;
    __syncthreads();
  }
  if ((int)threadIdx.x < nn) {
    row_start[node_lo + threadIdx.x] = lo + (lscan[threadIdx.x] - v);
    cnt[node_lo + threadIdx.x] = v;
  }
  if (blockIdx.x == 0 && threadIdx.x == 0) row_start[n] = e;
  if (threadIdx.x < 128) lcur[threadIdx.x] = lscan[threadIdx.x] - v;
  __syncthreads();
  if (sz <= LCAP) {
    for (int j = threadIdx.x; j < sz; j += 256) {
      unsigned r = stream[lo + j];
      int slot = atomicAdd(&lcur[r & BKM], 1);
      lbuf[slot] = (int)(r >> BKB);
    }
    __syncthreads();
    for (int j = threadIdx.x; j < sz; j += 256)
      csr_src[lo + j] = lbuf[j];
  } else {  // overflow fallback (statistically unreachable)
    for (int j = threadIdx.x; j < sz; j += 256) {
      unsigned r = stream[lo + j];
      int slot = atomicAdd(&lcur[r & BKM], 1);
      csr_src[lo + slot] = (int)(r >> BKB);
    }
  }
}

// ---------------- GEMM: 2-node x 4-out register tile, W in LDS ----------------
// Scaling lives in gcn_agg epilogues (round-16), so no cnt here.
// NOTE (round-7): no full unroll (hoists all W LDS loads). unroll 2.

template <int IN, int OUT, bool ATT>
__global__ __launch_bounds__(256) void gemm2x4(const unsigned short* __restrict__ Hh,
                                               const float* __restrict__ W,
                                               const float* __restrict__ att_src,
                                               const float* __restrict__ att_dst,
                                               unsigned short* __restrict__ T,
                                               float* __restrict__ a_s,
                                               float* __restrict__ a_d, int n) {
  constexpr int TX = OUT / 4;
  constexpr int NB = (256 / TX) * 2;
  __shared__ float Ws[IN * OUT];
  __shared__ float asv[ATT ? OUT : 1], adv[ATT ? OUT : 1];
  __shared__ float lds_as[ATT ? NB * 4 : 1], lds_ad[ATT ? NB * 4 : 1];

  for (int idx = threadIdx.x; idx < IN * OUT / 4; idx += 256)
    reinterpret_cast<float4*>(Ws)[idx] = reinterpret_cast<const float4*>(W)[idx];
  if (ATT) {
    if (threadIdx.x < OUT) {
      asv[threadIdx.x] = att_src[threadIdx.x];
      adv[threadIdx.x] = att_dst[threadIdx.x];
    }
    for (int idx = threadIdx.x; idx < NB * 4; idx += 256) {
      lds_as[idx] = 0.f; lds_ad[idx] = 0.f;
    }
  }
  __syncthreads();

  int tx = threadIdx.x % TX;
  int ty = threadIdx.x / TX;
  int j0 = tx * 4;
  int base = blockIdx.x * NB;
  int n0 = base + ty * 2;

  const unsigned short* h0p = Hh + (size_t)min(n0 + 0, n - 1) * IN;
  const unsigned short* h1p = Hh + (size_t)min(n0 + 1, n - 1) * IN;

  float4 acc0 = {0,0,0,0}, acc1 = {0,0,0,0};
#pragma unroll 2
  for (int k = 0; k < IN; k += 4) {
    uint2 va = *reinterpret_cast<const uint2*>(h0p + k);
    uint2 vb = *reinterpret_cast<const uint2*>(h1p + k);
    float2 a01 = __half22float2(u2h(va.x)), a23 = __half22float2(u2h(va.y));
    float2 b01 = __half22float2(u2h(vb.x)), b23 = __half22float2(u2h(vb.y));
    float4 ha = {a01.x, a01.y, a23.x, a23.y};
    float4 hb = {b01.x, b01.y, b23.x, b23.y};
    float4 w0 = *reinterpret_cast<const float4*>(&Ws[(k + 0) * OUT + j0]);
    float4 w1 = *reinterpret_cast<const float4*>(&Ws[(k + 1) * OUT + j0]);
    float4 w2 = *reinterpret_cast<const float4*>(&Ws[(k + 2) * OUT + j0]);
    float4 w3 = *reinterpret_cast<const float4*>(&Ws[(k + 3) * OUT + j0]);
#define A4(A, HV)                                                                \
    A.x = fmaf(HV.x, w0.x, A.x); A.y = fmaf(HV.x, w0.y, A.y);                    \
    A.z = fmaf(HV.x, w0.z, A.z); A.w = fmaf(HV.x, w0.w, A.w);                    \
    A.x = fmaf(HV.y, w1.x, A.x); A.y = fmaf(HV.y, w1.y, A.y);                    \
    A.z = fmaf(HV.y, w1.z, A.z); A.w = fmaf(HV.y, w1.w, A.w);                    \
    A.x = fmaf(HV.z, w2.x, A.x); A.y = fmaf(HV.z, w2.y, A.y);                    \
    A.z = fmaf(HV.z, w2.z, A.z); A.w = fmaf(HV.z, w2.w, A.w);                    \
    A.x = fmaf(HV.w, w3.x, A.x); A.y = fmaf(HV.w, w3.y, A.y);                    \
    A.z = fmaf(HV.w, w3.z, A.z); A.w = fmaf(HV.w, w3.w, A.w);
    A4(acc0, ha) A4(acc1, hb)
#undef A4
  }

  float4 av[2] = {acc0, acc1};
#pragma unroll
  for (int i = 0; i < 2; ++i) {
    int node = n0 + i;
    if (node < n) {
      float o0 = av[i].x, o1 = av[i].y, o2 = av[i].z, o3 = av[i].w;
      uint2 st;
      st.x = h2u(__floats2half2_rn(o0, o1));
      st.y = h2u(__floats2half2_rn(o2, o3));
      *reinterpret_cast<uint2*>(T + (size_t)node * OUT + j0) = st;
      if (ATT) {
        int head = tx >> 2;
        float cs = o0 * asv[j0] + o1 * asv[j0 + 1] + o2 * asv[j0 + 2] + o3 * asv[j0 + 3];
        float cd = o0 * adv[j0] + o1 * adv[j0 + 1] + o2 * adv[j0 + 2] + o3 * adv[j0 + 3];
        atomicAdd(&lds_as[(ty * 2 + i) * 4 + head], cs);
        atomicAdd(&lds_ad[(ty * 2 + i) * 4 + head], cd);
      }
    }
  }
  if (ATT) {
    __syncthreads();
    for (int idx = threadIdx.x; idx < NB * 4; idx += 256) {
      int node = base + (idx >> 2);
      if (node < n) {
        a_s[(size_t)base * 4 + idx] = lds_as[idx];
        a_d[(size_t)base * 4 + idx] = lds_ad[idx];
      }
    }
  }
}

// ---------------- GCN aggregate ----------------
// Round-16 scaling scheme (algebraically exact vs reference):
//   layer 1: T1 unscaled; DINV=true -> per-edge w = rsqrt(cnt[s]+1) via hfma2.
//   layers 1,2 (PRE=true): store dn*relu(dn*a+b).
//   layer 3 (PRE=false): store plain relu (feeds GAT).

template <int C, bool DINV, bool PRE>
__global__ __launch_bounds__(256) void gcn_agg(const unsigned short* __restrict__ T,
                                               const int* __restrict__ row_start,
                                               const int* __restrict__ csr_src,
                                               const int* __restrict__ cnt,
                                               const float* __restrict__ b,
                                               unsigned short* __restrict__ out, int n) {
  constexpr int LPR = C / 8;
  constexpr int SLOTS = 64 / LPR;
  constexpr unsigned RS4 = C / 8;
  int wid = threadIdx.x >> 6;
  int lane = threadIdx.x & 63;
  int node = blockIdx.x * 4 + wid;
  if (node >= n) return;
  int q = lane & (LPR - 1);
  int g = lane / LPR;
  const uint4* Tp = reinterpret_cast<const uint4*>(T);
  int rs = row_start[node], re = row_start[node + 1];
  float dn = rsqrtf((float)(cnt[node] + 1));
  __half2 A0 = u2h(0u), A1 = u2h(0u), A2 = u2h(0u), A3 = u2h(0u);
  if (g == 0) {  // self-loop
    uint4 v = Tp[(unsigned)node * RS4 + q];
    if constexpr (DINV) {
      __half2 hw = __float2half2_rn(dn);
      A0 = __hmul2(hw, u2h(v.x)); A1 = __hmul2(hw, u2h(v.y));
      A2 = __hmul2(hw, u2h(v.z)); A3 = __hmul2(hw, u2h(v.w));
    } else {
      A0 = u2h(v.x); A1 = u2h(v.y); A2 = u2h(v.z); A3 = u2h(v.w);
    }
  }
  if constexpr (C == 64) {
    __half2 B0 = u2h(0u), B1 = u2h(0u), B2 = u2h(0u), B3 = u2h(0u);
    int i = rs + g;
    while (i < re) {
      bool v2 = (i + 8) < re;
      unsigned s1 = (unsigned)csr_src[i];
      unsigned s2 = v2 ? (unsigned)csr_src[i + 8] : s1;
      uint4 r1 = Tp[s1 * RS4 + q];
      uint4 r2 = Tp[s2 * RS4 + q];
      if constexpr (DINV) {
        float w1f = rsqrtf((float)(cnt[s1] + 1));
        float w2f = v2 ? rsqrtf((float)(cnt[s2] + 1)) : 0.f;
        __half2 hw1 = __float2half2_rn(w1f);
        __half2 hw2 = __float2half2_rn(w2f);
        A0 = __hfma2(hw1, u2h(r1.x), A0); A1 = __hfma2(hw1, u2h(r1.y), A1);
        A2 = __hfma2(hw1, u2h(r1.z), A2); A3 = __hfma2(hw1, u2h(r1.w), A3);
        B0 = __hfma2(hw2, u2h(r2.x), B0); B1 = __hfma2(hw2, u2h(r2.y), B1);
        B2 = __hfma2(hw2, u2h(r2.z), B2); B3 = __hfma2(hw2, u2h(r2.w), B3);
      } else {
        if (!v2) { r2.x = 0u; r2.y = 0u; r2.z = 0u; r2.w = 0u; }
        A0 = __hadd2(A0, u2h(r1.x)); A1 = __hadd2(A1, u2h(r1.y));
        A2 = __hadd2(A2, u2h(r1.z)); A3 = __hadd2(A3, u2h(r1.w));
        B0 = __hadd2(B0, u2h(r2.x)); B1 = __hadd2(B1, u2h(r2.y));
        B2 = __hadd2(B2, u2h(r2.z)); B3 = __hadd2(B3, u2h(r2.w));
      }
      i += 16;
    }
    A0 = __hadd2(A0, B0); A1 = __hadd2(A1, B1);
    A2 = __hadd2(A2, B2); A3 = __hadd2(A3, B3);
  } else {
    for (int i = rs + g; i < re; i += SLOTS) {
      unsigned s = (unsigned)csr_src[i];
      uint4 v = Tp[s * RS4 + q];
      A0 = __hadd2(A0, u2h(v.x)); A1 = __hadd2(A1, u2h(v.y));
      A2 = __hadd2(A2, u2h(v.z)); A3 = __hadd2(A3, u2h(v.w));
    }
  }
#pragma unroll
  for (int off = LPR; off < 64; off <<= 1) {
    A0 = __hadd2(A0, shfl_h2(A0, off));
    A1 = __hadd2(A1, shfl_h2(A1, off));
    A2 = __hadd2(A2, shfl_h2(A2, off));
    A3 = __hadd2(A3, shfl_h2(A3, off));
  }
  if (lane < LPR) {
    float4 b0 = *reinterpret_cast<const float4*>(b + 8 * q);
    float4 b1 = *reinterpret_cast<const float4*>(b + 8 * q + 4);
    float2 f0 = __half22float2(A0), f1 = __half22float2(A1);
    float2 f2 = __half22float2(A2), f3 = __half22float2(A3);
    float sc = PRE ? dn : 1.f;
    float r0 = sc * fmaxf(fmaf(dn, f0.x, b0.x), 0.f);
    float r1 = sc * fmaxf(fmaf(dn, f0.y, b0.y), 0.f);
    float r2 = sc * fmaxf(fmaf(dn, f1.x, b0.z), 0.f);
    float r3 = sc * fmaxf(fmaf(dn, f1.y, b0.w), 0.f);
    float r4 = sc * fmaxf(fmaf(dn, f2.x, b1.x), 0.f);
    float r5 = sc * fmaxf(fmaf(dn, f2.y, b1.y), 0.f);
    float r6 = sc * fmaxf(fmaf(dn, f3.x, b1.z), 0.f);
    float r7 = sc * fmaxf(fmaf(dn, f3.y, b1.w), 0.f);
    uint4 o;
    o.x = h2u(__floats2half2_rn(r0, r1));
    o.y = h2u(__floats2half2_rn(r2, r3));
    o.z = h2u(__floats2half2_rn(r4, r5));
    o.w = h2u(__floats2half2_rn(r6, r7));
    reinterpret_cast<uint4*>(out)[(unsigned)node * RS4 + q] = o;
  }
}

// ---------------- GAT aggregate + fused mean-pool partial ----------------

__device__ __forceinline__ float lrelu(float v) { return v > 0.f ? v : 0.2f * v; }

__global__ __launch_bounds__(256) void gat_agg(const unsigned short* __restrict__ g,
                                               const float* __restrict__ a_s,
                                               const float* __restrict__ a_d,
                                               const int* __restrict__ row_start,
                                               const int* __restrict__ csr_src,
                                               const float* __restrict__ bg,
                                               float* __restrict__ partial1, int n) {
  __shared__ float pacc[4][64];
  int wid = threadIdx.x >> 6;
  int lane = threadIdx.x & 63;
  int node = blockIdx.x * 4 + wid;
  bool active = node < n;
  int q = lane & 7;
  int gslot = lane >> 3;
  int h = q >> 1;
  const uint4* gp = reinterpret_cast<const uint4*>(g);
  int rs = 0, re = 0;
  float ad_h = 0.f;
  if (active) {
    rs = row_start[node];
    re = row_start[node + 1];
    ad_h = a_d[(unsigned)node * 4u + h];
  }
  float den = 0.f, den2 = 0.f;
  __half2 A0 = u2h(0u), A1 = u2h(0u), A2 = u2h(0u), A3 = u2h(0u);
  __half2 C0 = u2h(0u), C1 = u2h(0u), C2 = u2h(0u), C3 = u2h(0u);
  if (active && gslot == 0) {  // self-loop
    float w = __expf(lrelu(a_s[(unsigned)node * 4u + h] + ad_h));
    uint4 v = gp[(unsigned)node * 8u + q];
    den = w;
    __half2 w2 = __float2half2_rn(w);
    A0 = __hmul2(w2, u2h(v.x)); A1 = __hmul2(w2, u2h(v.y));
    A2 = __hmul2(w2, u2h(v.z)); A3 = __hmul2(w2, u2h(v.w));
  }
  int i = rs + gslot;
  while (i < re) {
    bool v2 = (i + 8) < re;
    unsigned s1 = (unsigned)csr_src[i];
    unsigned s2 = v2 ? (unsigned)csr_src[i + 8] : s1;
    float e1 = a_s[s1 * 4u + h];
    float e2 = a_s[s2 * 4u + h];
    uint4 r1 = gp[s1 * 8u + q];
    uint4 r2 = gp[s2 * 8u + q];
    float w1 = __expf(lrelu(e1 + ad_h));
    float w2 = v2 ? __expf(lrelu(e2 + ad_h)) : 0.f;
    den += w1;
    den2 += w2;
    __half2 hw1 = __float2half2_rn(w1);
    __half2 hw2 = __float2half2_rn(w2);
    A0 = __hfma2(hw1, u2h(r1.x), A0); A1 = __hfma2(hw1, u2h(r1.y), A1);
    A2 = __hfma2(hw1, u2h(r1.z), A2); A3 = __hfma2(hw1, u2h(r1.w), A3);
    C0 = __hfma2(hw2, u2h(r2.x), C0); C1 = __hfma2(hw2, u2h(r2.y), C1);
    C2 = __hfma2(hw2, u2h(r2.z), C2); C3 = __hfma2(hw2, u2h(r2.w), C3);
    i += 16;
  }
  den += den2;
  A0 = __hadd2(A0, C0); A1 = __hadd2(A1, C1);
  A2 = __hadd2(A2, C2); A3 = __hadd2(A3, C3);
#pragma unroll
  for (int off = 8; off < 64; off <<= 1) {
    den += __shfl_xor(den, off);
    A0 = __hadd2(A0, shfl_h2(A0, off));
    A1 = __hadd2(A1, shfl_h2(A1, off));
    A2 = __hadd2(A2, shfl_h2(A2, off));
    A3 = __hadd2(A3, shfl_h2(A3, off));
  }
  if (lane < 8) {
    float inv = active ? (1.f / den) : 0.f;
    float4 b0 = *reinterpret_cast<const float4*>(bg + 8 * q);
    float4 b1 = *reinterpret_cast<const float4*>(bg + 8 * q + 4);
    float2 f0 = __half22float2(A0), f1 = __half22float2(A1);
    float2 f2 = __half22float2(A2), f3 = __half22float2(A3);
    int c0 = 8 * q;
    pacc[wid][c0 + 0] = active ? fmaxf(fmaf(f0.x, inv, b0.x), 0.f) : 0.f;
    pacc[wid][c0 + 1] = active ? fmaxf(fmaf(f0.y, inv, b0.y), 0.f) : 0.f;
    pacc[wid][c0 + 2] = active ? fmaxf(fmaf(f1.x, inv, b0.z), 0.f) : 0.f;
    pacc[wid][c0 + 3] = active ? fmaxf(fmaf(f1.y, inv, b0.w), 0.f) : 0.f;
    pacc[wid][c0 + 4] = active ? fmaxf(fmaf(f2.x, inv, b1.x), 0.f) : 0.f;
    pacc[wid][c0 + 5] = active ? fmaxf(fmaf(f2.y, inv, b1.y), 0.f) : 0.f;
    pacc[wid][c0 + 6] = active ? fmaxf(fmaf(f3.x, inv, b1.z), 0.f) : 0.f;
    pacc[wid][c0 + 7] = active ? fmaxf(fmaf(f3.y, inv, b1.w), 0.f) : 0.f;
  }
  __syncthreads();
  if (threadIdx.x < 64) {
    int t = threadIdx.x;
    partial1[(size_t)blockIdx.x * 64 + t] =
        pacc[0][t] + pacc[1][t] + pacc[2][t] + pacc[3][t];
  }
}

// ---------------- pooling + classifier ----------------

#define PBLK 512

__global__ __launch_bounds__(256) void pool_partial(const float* __restrict__ P1,
                                                    double* __restrict__ partial2,
                                                    unsigned total) {
  unsigned tid = blockIdx.x * 256u + threadIdx.x;
  unsigned stride = PBLK * 256u;
  double a = 0.0;
  for (unsigned i = tid; i < total; i += stride) a += (double)P1[i];
  __shared__ double red[256];
  red[threadIdx.x] = a;
  __syncthreads();
  if (threadIdx.x < 64) {
    int t = threadIdx.x;
    double s = red[t] + red[t + 64] + red[t + 128] + red[t + 192];
    partial2[(size_t)blockIdx.x * 64 + t] = s;
  }
}

__global__ __launch_bounds__(64) void final_kernel(const double* __restrict__ partial, int nblocks,
                                                   const float* __restrict__ Wc1,
                                                   const float* __restrict__ bc1,
                                                   const float* __restrict__ Wc2,
                                                   const float* __restrict__ bc2,
                                                   float* __restrict__ out, int n) {
  __shared__ float pooled[64];
  __shared__ float z[32];
  int t = threadIdx.x;
  double s = 0.0;
#pragma unroll 4
  for (int b = 0; b < nblocks; ++b) s += partial[(size_t)b * 64 + t];
  pooled[t] = (float)(s / (double)n);
  __syncthreads();
  if (t < 32) {
    double a = 0.0;
    for (int k = 0; k < 64; ++k) a += (double)pooled[k] * (double)Wc1[k * 32 + t];
    z[t] = fmaxf((float)a + bc1[t], 0.f);
  }
  __syncthreads();
  if (t < 2) {
    double a = 0.0;
    for (int j = 0; j < 32; ++j) a += (double)z[j] * (double)Wc2[j * 2 + t];
    out[t] = (float)a + bc2[t];
  }
}

// ---------------- launch ----------------

extern "C" void kernel_launch(void* const* d_in, const int* in_sizes, int n_in,
                              void* d_out, int out_size, void* d_ws, size_t ws_size,
                              hipStream_t stream) {
  const float* x   = (const float*)d_in[0];
  const int* eidx  = (const int*)d_in[1];
  const float* W1  = (const float*)d_in[2];
  const float* b1  = (const float*)d_in[3];
  const float* W2  = (const float*)d_in[4];
  const float* b2  = (const float*)d_in[5];
  const float* W3  = (const float*)d_in[6];
  const float* b3  = (const float*)d_in[7];
  const float* Wg  = (const float*)d_in[8];
  const float* att_src = (const float*)d_in[9];
  const float* att_dst = (const float*)d_in[10];
  const float* bg  = (const float*)d_in[11];
  const float* Wc1 = (const float*)d_in[12];
  const float* bc1 = (const float*)d_in[13];
  const float* Wc2 = (const float*)d_in[14];
  const float* bc2 = (const float*)d_in[15];

  const int n = in_sizes[0] / 64;   // 100000
  const int e = in_sizes[1] / 2;    // 1200000
  const int* src = eidx;
  const int* dst = eidx + e;

  char* ws = (char*)d_ws;
  size_t off = 0;
  auto alloc = [&](size_t bytes) {
    void* p = ws + off;
    off += (bytes + 255) & ~(size_t)255;
    return p;
  };
  const int nbuckets = (n + BKM) >> BKB;   // 782
  const int nblk4 = (n + 3) / 4;
  int*      cnt        = (int*)alloc((size_t)n * 4);
  int*      row_start  = (int*)alloc(((size_t)n + 1) * 4);
  unsigned* stream_b   = (unsigned*)alloc((size_t)e * 4);
  int*      csr_src    = (int*)alloc((size_t)e * 4);
  int*      bcnt       = (int*)alloc(NBK * 4);
  int*      bucket_base = (int*)alloc((NBK + 1) * 4);
  int*      gcursor    = (int*)alloc(NBK * 4);
  unsigned short* bufT = (unsigned short*)alloc((size_t)n * 64 * 2);  // fp16 messages
  unsigned short* bufF = (unsigned short*)alloc((size_t)n * 64 * 2);  // fp16 activations
  float*    a_s        = (float*)alloc((size_t)n * 4 * 4);
  float*    a_d        = (float*)alloc((size_t)n * 4 * 4);
  float*    partial1   = (float*)alloc((size_t)nblk4 * 64 * 4);
  double*   partial2   = (double*)alloc((size_t)PBLK * 64 * 8);

  hipMemsetAsync(bcnt, 0, NBK * 4, stream);

  int g64 = (n + 31) / 32;    // gemm2x4 OUT=64: 32 nodes/block
  int g32 = (n + 63) / 64;    // gemm2x4 OUT=32: 64 nodes/block
  int p1blk = (e + 256 * P1E - 1) / (256 * P1E);   // 1172

  // graph build; gemm1 (scale-free) fused into the histogram dispatch
  hist_gemm1<<<p1blk + g64, 256, 0, stream>>>(dst, bcnt, e, p1blk, x, W1, bufT, n);
  bucket_scan<<<1, 1024, 0, stream>>>(bcnt, bucket_base, gcursor, nbuckets, e);
  bin_pass1<<<p1blk, 256, 0, stream>>>(src, dst, gcursor, stream_b, e);
  bin_pass2<<<nbuckets, 256, 0, stream>>>(stream_b, bucket_base, row_start, cnt,
                                          csr_src, n, e);

  // GCN layer 1 (per-edge dinv; pre-scaled output)
  gcn_agg<64, true, true><<<nblk4, 256, 0, stream>>>(bufT, row_start, csr_src, cnt, b1, bufF, n);
  // GCN layer 2
  gemm2x4<64, 64, false><<<g64, 256, 0, stream>>>(bufF, W2, nullptr, nullptr,
                                                  bufT, nullptr, nullptr, n);
  gcn_agg<64, false, true><<<nblk4, 256, 0, stream>>>(bufT, row_start, csr_src, cnt, b2, bufF, n);
  // GCN layer 3 -> 32 channels (plain output for GAT)
  gemm2x4<64, 32, false><<<g32, 256, 0, stream>>>(bufF, W3, nullptr, nullptr,
                                                  bufT, nullptr, nullptr, n);
  gcn_agg<32, false, false><<<nblk4, 256, 0, stream>>>(bufT, row_start, csr_src, cnt, b3, bufF, n);
  // GAT projection + fused a_s/a_d
  gemm2x4<32, 64, true><<<g64, 256, 0, stream>>>(bufF, Wg, att_src, att_dst,
                                                 bufT, a_s, a_d, n);
  // GAT aggregate with fused mean-pool partials
  gat_agg<<<nblk4, 256, 0, stream>>>(bufT, a_s, a_d, row_start, csr_src, bg, partial1, n);
  // pool + MLP
  pool_partial<<<PBLK, 256, 0, stream>>>(partial1, partial2, (unsigned)nblk4 * 64u);
  final_kernel<<<1, 64, 0, stream>>>(partial2, PBLK, Wc1, bc1, Wc2, bc2, (float*)d_out, n);
}

// Round 20
// 315.587 us; speedup vs baseline: 1.1372x; 1.1372x over previous
//
#include <hip/hip_runtime.h>
#include <hip/hip_bf16.h>
#include <hip/hip_fp16.h>
#include <math.h>

// fp16 helpers — message/activation tables are fp16; packed half2 math keeps the
// gather inner loop at 4 VALU per uint4 (round-14).
__device__ __forceinline__ unsigned h2u(__half2 h) { return *reinterpret_cast<unsigned*>(&h); }
__device__ __forceinline__ __half2 u2h(unsigned u) { return *reinterpret_cast<__half2*>(&u); }
__device__ __forceinline__ __half2 shfl_h2(__half2 h, int off) {
  int v = __shfl_xor((int)h2u(h), off);
  unsigned uv = (unsigned)v;
  return u2h(uv);
}

// ---------------- graph build: bucket-sort CSR, no per-node atomics ----------------
// ROUND-17 LESSON: no block-barrier fusion of agg+gemm (kills wave load balance).
// ROUND-19 LESSON: P1E=4 + 800 buckets tripled bin_pass1 (940K contended global
// atomics; LDS histogram no longer amortizes). Keep P1E=16 / 256-node buckets:
// few fat blocks = small atomic count. This build config measured 316 us twice.

#define P1E 16   // edges per thread in pass 1
#define NBK 400  // max buckets (100k/256 = 391)

// fused: bucket histogram (blocks < fillBlocks) + layer-1 GEMM (rest).
__global__ __launch_bounds__(256) void hist_gemm1(const int* __restrict__ dst,
                                                  int* __restrict__ bcnt, int e,
                                                  int fillBlocks,
                                                  const float* __restrict__ H,
                                                  const float* __restrict__ W,
                                                  unsigned short* __restrict__ T, int n) {
  __shared__ int lcnt[NBK];
  __shared__ float Ws[64 * 64];
  if ((int)blockIdx.x < fillBlocks) {
    for (int i = threadIdx.x; i < NBK; i += 256) lcnt[i] = 0;
    __syncthreads();
    int base = blockIdx.x * (256 * P1E);
#pragma unroll
    for (int r = 0; r < P1E; ++r) {
      int i = base + r * 256 + threadIdx.x;
      if (i < e) atomicAdd(&lcnt[dst[i] >> 8], 1);
    }
    __syncthreads();
    for (int b = threadIdx.x; b < NBK; b += 256)
      if (lcnt[b]) atomicAdd(&bcnt[b], lcnt[b]);
    return;
  }
  // gemm1: IN=64 f32, OUT=64, UNSCALED (layer-1 agg applies dinv per edge)
  for (int idx = threadIdx.x; idx < 64 * 64 / 4; idx += 256)
    reinterpret_cast<float4*>(Ws)[idx] = reinterpret_cast<const float4*>(W)[idx];
  __syncthreads();
  int bid = blockIdx.x - fillBlocks;
  int tx = threadIdx.x % 16;
  int ty = threadIdx.x / 16;
  int j0 = tx * 4;
  int n0 = bid * 32 + ty * 2;
  const float* h0p = H + (size_t)min(n0 + 0, n - 1) * 64;
  const float* h1p = H + (size_t)min(n0 + 1, n - 1) * 64;
  float4 acc0 = {0,0,0,0}, acc1 = {0,0,0,0};
#pragma unroll 2
  for (int k = 0; k < 64; k += 4) {
    float4 ha = *reinterpret_cast<const float4*>(h0p + k);
    float4 hb = *reinterpret_cast<const float4*>(h1p + k);
    float4 w0 = *reinterpret_cast<const float4*>(&Ws[(k + 0) * 64 + j0]);
    float4 w1 = *reinterpret_cast<const float4*>(&Ws[(k + 1) * 64 + j0]);
    float4 w2 = *reinterpret_cast<const float4*>(&Ws[(k + 2) * 64 + j0]);
    float4 w3 = *reinterpret_cast<const float4*>(&Ws[(k + 3) * 64 + j0]);
#define A4(A, HV)                                                                \
    A.x = fmaf(HV.x, w0.x, A.x); A.y = fmaf(HV.x, w0.y, A.y);                    \
    A.z = fmaf(HV.x, w0.z, A.z); A.w = fmaf(HV.x, w0.w, A.w);                    \
    A.x = fmaf(HV.y, w1.x, A.x); A.y = fmaf(HV.y, w1.y, A.y);                    \
    A.z = fmaf(HV.y, w1.z, A.z); A.w = fmaf(HV.y, w1.w, A.w);                    \
    A.x = fmaf(HV.z, w2.x, A.x); A.y = fmaf(HV.z, w2.y, A.y);                    \
    A.z = fmaf(HV.z, w2.z, A.z); A.w = fmaf(HV.z, w2.w, A.w);                    \
    A.x = fmaf(HV.w, w3.x, A.x); A.y = fmaf(HV.w, w3.y, A.y);                    \
    A.z = fmaf(HV.w, w3.z, A.z); A.w = fmaf(HV.w, w3.w, A.w);
    A4(acc0, ha) A4(acc1, hb)
#undef A4
  }
  float4 av[2] = {acc0, acc1};
#pragma unroll
  for (int i = 0; i < 2; ++i) {
    int node = n0 + i;
    if (node < n) {
      uint2 st;
      st.x = h2u(__floats2half2_rn(av[i].x, av[i].y));
      st.y = h2u(__floats2half2_rn(av[i].z, av[i].w));
      *reinterpret_cast<uint2*>(T + (size_t)node * 64 + j0) = st;
    }
  }
}

__global__ __launch_bounds__(512) void bucket_scan(const int* __restrict__ bcnt,
                                                   int* __restrict__ bucket_base,
                                                   int* __restrict__ gcursor,
                                                   int nb, int e) {
  __shared__ int s[512];
  int v = (threadIdx.x < (unsigned)nb) ? bcnt[threadIdx.x] : 0;
  s[threadIdx.x] = v;
  __syncthreads();
  for (int off = 1; off < 512; off <<= 1) {
    int t = (threadIdx.x >= (unsigned)off) ? s[threadIdx.x - off] : 0;
    __syncthreads();
    s[threadIdx.x] += t;
    __syncthreads();
  }
  if (threadIdx.x < (unsigned)nb) {
    int excl = s[threadIdx.x] - v;
    bucket_base[threadIdx.x] = excl;
    gcursor[threadIdx.x] = excl;
  }
  if (threadIdx.x == 0) bucket_base[nb] = e;
}

__global__ __launch_bounds__(256) void bin_pass1(const int* __restrict__ src,
                                                 const int* __restrict__ dst,
                                                 int* __restrict__ gcursor,
                                                 unsigned* __restrict__ stream, int e) {
  __shared__ int lcnt[NBK], gbase[NBK];
  for (int i = threadIdx.x; i < NBK; i += 256) lcnt[i] = 0;
  __syncthreads();
  int base = blockIdx.x * (256 * P1E);
  int rankr[P1E];
#pragma unroll
  for (int r = 0; r < P1E; ++r) {
    int i = base + r * 256 + threadIdx.x;
    rankr[r] = (i < e) ? atomicAdd(&lcnt[dst[i] >> 8], 1) : 0;
  }
  __syncthreads();
  for (int bkt = threadIdx.x; bkt < NBK; bkt += 256)
    gbase[bkt] = lcnt[bkt] ? atomicAdd(&gcursor[bkt], lcnt[bkt]) : 0;
  __syncthreads();
#pragma unroll
  for (int r = 0; r < P1E; ++r) {
    int i = base + r * 256 + threadIdx.x;
    if (i < e) {
      int d = dst[i];
      stream[gbase[d >> 8] + rankr[r]] = ((unsigned)src[i] << 8) | (unsigned)(d & 255);
    }
  }
}

#define LCAP 6144

__global__ __launch_bounds__(256) void bin_pass2(const unsigned* __restrict__ stream,
                                                 const int* __restrict__ bucket_base,
                                                 int* __restrict__ row_start,
                                                 int* __restrict__ cnt,
                                                 int* __restrict__ csr_src,
                                                 int n, int e) {
  __shared__ int lcnt[256];
  __shared__ int lscan[256];
  __shared__ int lcur[256];
  __shared__ int lbuf[LCAP];
  int node_lo = blockIdx.x << 8;
  int nn = min(256, n - node_lo);
  int lo = bucket_base[blockIdx.x];
  int hi = bucket_base[blockIdx.x + 1];
  int sz = hi - lo;
  lcnt[threadIdx.x] = 0;
  __syncthreads();
  for (int j = threadIdx.x; j < sz; j += 256)
    atomicAdd(&lcnt[stream[lo + j] & 255], 1);
  __syncthreads();
  int v = lcnt[threadIdx.x];
  lscan[threadIdx.x] = v;
  __syncthreads();
  for (int off = 1; off < 256; off <<= 1) {
    int t = (threadIdx.x >= (unsigned)off) ? lscan[threadIdx.x - off] : 0;
    __syncthreads();
    lscan[threadIdx.x] += t;
    __syncthreads();
  }
  int excl = lscan[threadIdx.x] - v;
  if ((int)threadIdx.x < nn) {
    row_start[node_lo + threadIdx.x] = lo + excl;
    cnt[node_lo + threadIdx.x] = v;
  }
  if (blockIdx.x == 0 && threadIdx.x == 0) row_start[n] = e;
  lcur[threadIdx.x] = excl;
  __syncthreads();
  if (sz <= LCAP) {
    for (int j = threadIdx.x; j < sz; j += 256) {
      unsigned r = stream[lo + j];
      int slot = atomicAdd(&lcur[r & 255], 1);
      lbuf[slot] = (int)(r >> 8);
    }
    __syncthreads();
    for (int j = threadIdx.x; j < sz; j += 256)
      csr_src[lo + j] = lbuf[j];
  } else {
    for (int j = threadIdx.x; j < sz; j += 256) {
      unsigned r = stream[lo + j];
      int slot = atomicAdd(&lcur[r & 255], 1);
      csr_src[lo + slot] = (int)(r >> 8);
    }
  }
}

// ---------------- GEMM: 2-node x 4-out register tile, W in LDS ----------------
// Scaling lives in gcn_agg epilogues (round-16), so no cnt here.
// NOTE (round-7): no full unroll (hoists all W LDS loads). unroll 2.

template <int IN, int OUT, bool ATT>
__global__ __launch_bounds__(256) void gemm2x4(const unsigned short* __restrict__ Hh,
                                               const float* __restrict__ W,
                                               const float* __restrict__ att_src,
                                               const float* __restrict__ att_dst,
                                               unsigned short* __restrict__ T,
                                               float* __restrict__ a_s,
                                               float* __restrict__ a_d, int n) {
  constexpr int TX = OUT / 4;
  constexpr int NB = (256 / TX) * 2;
  __shared__ float Ws[IN * OUT];
  __shared__ float asv[ATT ? OUT : 1], adv[ATT ? OUT : 1];
  __shared__ float lds_as[ATT ? NB * 4 : 1], lds_ad[ATT ? NB * 4 : 1];

  for (int idx = threadIdx.x; idx < IN * OUT / 4; idx += 256)
    reinterpret_cast<float4*>(Ws)[idx] = reinterpret_cast<const float4*>(W)[idx];
  if (ATT) {
    if (threadIdx.x < OUT) {
      asv[threadIdx.x] = att_src[threadIdx.x];
      adv[threadIdx.x] = att_dst[threadIdx.x];
    }
    for (int idx = threadIdx.x; idx < NB * 4; idx += 256) {
      lds_as[idx] = 0.f; lds_ad[idx] = 0.f;
    }
  }
  __syncthreads();

  int tx = threadIdx.x % TX;
  int ty = threadIdx.x / TX;
  int j0 = tx * 4;
  int base = blockIdx.x * NB;
  int n0 = base + ty * 2;

  const unsigned short* h0p = Hh + (size_t)min(n0 + 0, n - 1) * IN;
  const unsigned short* h1p = Hh + (size_t)min(n0 + 1, n - 1) * IN;

  float4 acc0 = {0,0,0,0}, acc1 = {0,0,0,0};
#pragma unroll 2
  for (int k = 0; k < IN; k += 4) {
    uint2 va = *reinterpret_cast<const uint2*>(h0p + k);
    uint2 vb = *reinterpret_cast<const uint2*>(h1p + k);
    float2 a01 = __half22float2(u2h(va.x)), a23 = __half22float2(u2h(va.y));
    float2 b01 = __half22float2(u2h(vb.x)), b23 = __half22float2(u2h(vb.y));
    float4 ha = {a01.x, a01.y, a23.x, a23.y};
    float4 hb = {b01.x, b01.y, b23.x, b23.y};
    float4 w0 = *reinterpret_cast<const float4*>(&Ws[(k + 0) * OUT + j0]);
    float4 w1 = *reinterpret_cast<const float4*>(&Ws[(k + 1) * OUT + j0]);
    float4 w2 = *reinterpret_cast<const float4*>(&Ws[(k + 2) * OUT + j0]);
    float4 w3 = *reinterpret_cast<const float4*>(&Ws[(k + 3) * OUT + j0]);
#define A4(A, HV)                                                                \
    A.x = fmaf(HV.x, w0.x, A.x); A.y = fmaf(HV.x, w0.y, A.y);                    \
    A.z = fmaf(HV.x, w0.z, A.z); A.w = fmaf(HV.x, w0.w, A.w);                    \
    A.x = fmaf(HV.y, w1.x, A.x); A.y = fmaf(HV.y, w1.y, A.y);                    \
    A.z = fmaf(HV.y, w1.z, A.z); A.w = fmaf(HV.y, w1.w, A.w);                    \
    A.x = fmaf(HV.z, w2.x, A.x); A.y = fmaf(HV.z, w2.y, A.y);                    \
    A.z = fmaf(HV.z, w2.z, A.z); A.w = fmaf(HV.z, w2.w, A.w);                    \
    A.x = fmaf(HV.w, w3.x, A.x); A.y = fmaf(HV.w, w3.y, A.y);                    \
    A.z = fmaf(HV.w, w3.z, A.z); A.w = fmaf(HV.w, w3.w, A.w);
    A4(acc0, ha) A4(acc1, hb)
#undef A4
  }

  float4 av[2] = {acc0, acc1};
#pragma unroll
  for (int i = 0; i < 2; ++i) {
    int node = n0 + i;
    if (node < n) {
      float o0 = av[i].x, o1 = av[i].y, o2 = av[i].z, o3 = av[i].w;
      uint2 st;
      st.x = h2u(__floats2half2_rn(o0, o1));
      st.y = h2u(__floats2half2_rn(o2, o3));
      *reinterpret_cast<uint2*>(T + (size_t)node * OUT + j0) = st;
      if (ATT) {
        int head = tx >> 2;
        float cs = o0 * asv[j0] + o1 * asv[j0 + 1] + o2 * asv[j0 + 2] + o3 * asv[j0 + 3];
        float cd = o0 * adv[j0] + o1 * adv[j0 + 1] + o2 * adv[j0 + 2] + o3 * adv[j0 + 3];
        atomicAdd(&lds_as[(ty * 2 + i) * 4 + head], cs);
        atomicAdd(&lds_ad[(ty * 2 + i) * 4 + head], cd);
      }
    }
  }
  if (ATT) {
    __syncthreads();
    for (int idx = threadIdx.x; idx < NB * 4; idx += 256) {
      int node = base + (idx >> 2);
      if (node < n) {
        a_s[(size_t)base * 4 + idx] = lds_as[idx];
        a_d[(size_t)base * 4 + idx] = lds_ad[idx];
      }
    }
  }
}

// ---------------- GCN aggregate ----------------
// Round-16 scaling scheme (algebraically exact vs reference):
//   layer 1: T1 unscaled; DINV=true -> per-edge w = rsqrt(cnt[s]+1) via hfma2.
//   layers 1,2 (PRE=true): store dn*relu(dn*a+b).
//   layer 3 (PRE=false): store plain relu (feeds GAT).

template <int C, bool DINV, bool PRE>
__global__ __launch_bounds__(256) void gcn_agg(const unsigned short* __restrict__ T,
                                               const int* __restrict__ row_start,
                                               const int* __restrict__ csr_src,
                                               const int* __restrict__ cnt,
                                               const float* __restrict__ b,
                                               unsigned short* __restrict__ out, int n) {
  constexpr int LPR = C / 8;
  constexpr int SLOTS = 64 / LPR;
  constexpr unsigned RS4 = C / 8;
  int wid = threadIdx.x >> 6;
  int lane = threadIdx.x & 63;
  int node = blockIdx.x * 4 + wid;
  if (node >= n) return;
  int q = lane & (LPR - 1);
  int g = lane / LPR;
  const uint4* Tp = reinterpret_cast<const uint4*>(T);
  int rs = row_start[node], re = row_start[node + 1];
  float dn = rsqrtf((float)(cnt[node] + 1));
  __half2 A0 = u2h(0u), A1 = u2h(0u), A2 = u2h(0u), A3 = u2h(0u);
  if (g == 0) {  // self-loop
    uint4 v = Tp[(unsigned)node * RS4 + q];
    if constexpr (DINV) {
      __half2 hw = __float2half2_rn(dn);
      A0 = __hmul2(hw, u2h(v.x)); A1 = __hmul2(hw, u2h(v.y));
      A2 = __hmul2(hw, u2h(v.z)); A3 = __hmul2(hw, u2h(v.w));
    } else {
      A0 = u2h(v.x); A1 = u2h(v.y); A2 = u2h(v.z); A3 = u2h(v.w);
    }
  }
  if constexpr (C == 64) {
    __half2 B0 = u2h(0u), B1 = u2h(0u), B2 = u2h(0u), B3 = u2h(0u);
    int i = rs + g;
    while (i < re) {
      bool v2 = (i + 8) < re;
      unsigned s1 = (unsigned)csr_src[i];
      unsigned s2 = v2 ? (unsigned)csr_src[i + 8] : s1;
      uint4 r1 = Tp[s1 * RS4 + q];
      uint4 r2 = Tp[s2 * RS4 + q];
      if constexpr (DINV) {
        float w1f = rsqrtf((float)(cnt[s1] + 1));
        float w2f = v2 ? rsqrtf((float)(cnt[s2] + 1)) : 0.f;
        __half2 hw1 = __float2half2_rn(w1f);
        __half2 hw2 = __float2half2_rn(w2f);
        A0 = __hfma2(hw1, u2h(r1.x), A0); A1 = __hfma2(hw1, u2h(r1.y), A1);
        A2 = __hfma2(hw1, u2h(r1.z), A2); A3 = __hfma2(hw1, u2h(r1.w), A3);
        B0 = __hfma2(hw2, u2h(r2.x), B0); B1 = __hfma2(hw2, u2h(r2.y), B1);
        B2 = __hfma2(hw2, u2h(r2.z), B2); B3 = __hfma2(hw2, u2h(r2.w), B3);
      } else {
        if (!v2) { r2.x = 0u; r2.y = 0u; r2.z = 0u; r2.w = 0u; }
        A0 = __hadd2(A0, u2h(r1.x)); A1 = __hadd2(A1, u2h(r1.y));
        A2 = __hadd2(A2, u2h(r1.z)); A3 = __hadd2(A3, u2h(r1.w));
        B0 = __hadd2(B0, u2h(r2.x)); B1 = __hadd2(B1, u2h(r2.y));
        B2 = __hadd2(B2, u2h(r2.z)); B3 = __hadd2(B3, u2h(r2.w));
      }
      i += 16;
    }
    A0 = __hadd2(A0, B0); A1 = __hadd2(A1, B1);
    A2 = __hadd2(A2, B2); A3 = __hadd2(A3, B3);
  } else {
    for (int i = rs + g; i < re; i += SLOTS) {
      unsigned s = (unsigned)csr_src[i];
      uint4 v = Tp[s * RS4 + q];
      A0 = __hadd2(A0, u2h(v.x)); A1 = __hadd2(A1, u2h(v.y));
      A2 = __hadd2(A2, u2h(v.z)); A3 = __hadd2(A3, u2h(v.w));
    }
  }
#pragma unroll
  for (int off = LPR; off < 64; off <<= 1) {
    A0 = __hadd2(A0, shfl_h2(A0, off));
    A1 = __hadd2(A1, shfl_h2(A1, off));
    A2 = __hadd2(A2, shfl_h2(A2, off));
    A3 = __hadd2(A3, shfl_h2(A3, off));
  }
  if (lane < LPR) {
    float4 b0 = *reinterpret_cast<const float4*>(b + 8 * q);
    float4 b1 = *reinterpret_cast<const float4*>(b + 8 * q + 4);
    float2 f0 = __half22float2(A0), f1 = __half22float2(A1);
    float2 f2 = __half22float2(A2), f3 = __half22float2(A3);
    float sc = PRE ? dn : 1.f;
    float r0 = sc * fmaxf(fmaf(dn, f0.x, b0.x), 0.f);
    float r1 = sc * fmaxf(fmaf(dn, f0.y, b0.y), 0.f);
    float r2 = sc * fmaxf(fmaf(dn, f1.x, b0.z), 0.f);
    float r3 = sc * fmaxf(fmaf(dn, f1.y, b0.w), 0.f);
    float r4 = sc * fmaxf(fmaf(dn, f2.x, b1.x), 0.f);
    float r5 = sc * fmaxf(fmaf(dn, f2.y, b1.y), 0.f);
    float r6 = sc * fmaxf(fmaf(dn, f3.x, b1.z), 0.f);
    float r7 = sc * fmaxf(fmaf(dn, f3.y, b1.w), 0.f);
    uint4 o;
    o.x = h2u(__floats2half2_rn(r0, r1));
    o.y = h2u(__floats2half2_rn(r2, r3));
    o.z = h2u(__floats2half2_rn(r4, r5));
    o.w = h2u(__floats2half2_rn(r6, r7));
    reinterpret_cast<uint4*>(out)[(unsigned)node * RS4 + q] = o;
  }
}

// ---------------- GAT aggregate + fused mean-pool partial ----------------

__device__ __forceinline__ float lrelu(float v) { return v > 0.f ? v : 0.2f * v; }

__global__ __launch_bounds__(256) void gat_agg(const unsigned short* __restrict__ g,
                                               const float* __restrict__ a_s,
                                               const float* __restrict__ a_d,
                                               const int* __restrict__ row_start,
                                               const int* __restrict__ csr_src,
                                               const float* __restrict__ bg,
                                               float* __restrict__ partial1, int n) {
  __shared__ float pacc[4][64];
  int wid = threadIdx.x >> 6;
  int lane = threadIdx.x & 63;
  int node = blockIdx.x * 4 + wid;
  bool active = node < n;
  int q = lane & 7;
  int gslot = lane >> 3;
  int h = q >> 1;
  const uint4* gp = reinterpret_cast<const uint4*>(g);
  int rs = 0, re = 0;
  float ad_h = 0.f;
  if (active) {
    rs = row_start[node];
    re = row_start[node + 1];
    ad_h = a_d[(unsigned)node * 4u + h];
  }
  float den = 0.f, den2 = 0.f;
  __half2 A0 = u2h(0u), A1 = u2h(0u), A2 = u2h(0u), A3 = u2h(0u);
  __half2 C0 = u2h(0u), C1 = u2h(0u), C2 = u2h(0u), C3 = u2h(0u);
  if (active && gslot == 0) {  // self-loop
    float w = __expf(lrelu(a_s[(unsigned)node * 4u + h] + ad_h));
    uint4 v = gp[(unsigned)node * 8u + q];
    den = w;
    __half2 w2 = __float2half2_rn(w);
    A0 = __hmul2(w2, u2h(v.x)); A1 = __hmul2(w2, u2h(v.y));
    A2 = __hmul2(w2, u2h(v.z)); A3 = __hmul2(w2, u2h(v.w));
  }
  int i = rs + gslot;
  while (i < re) {
    bool v2 = (i + 8) < re;
    unsigned s1 = (unsigned)csr_src[i];
    unsigned s2 = v2 ? (unsigned)csr_src[i + 8] : s1;
    float e1 = a_s[s1 * 4u + h];
    float e2 = a_s[s2 * 4u + h];
    uint4 r1 = gp[s1 * 8u + q];
    uint4 r2 = gp[s2 * 8u + q];
    float w1 = __expf(lrelu(e1 + ad_h));
    float w2 = v2 ? __expf(lrelu(e2 + ad_h)) : 0.f;
    den += w1;
    den2 += w2;
    __half2 hw1 = __float2half2_rn(w1);
    __half2 hw2 = __float2half2_rn(w2);
    A0 = __hfma2(hw1, u2h(r1.x), A0); A1 = __hfma2(hw1, u2h(r1.y), A1);
    A2 = __hfma2(hw1, u2h(r1.z), A2); A3 = __hfma2(hw1, u2h(r1.w), A3);
    C0 = __hfma2(hw2, u2h(r2.x), C0); C1 = __hfma2(hw2, u2h(r2.y), C1);
    C2 = __hfma2(hw2, u2h(r2.z), C2); C3 = __hfma2(hw2, u2h(r2.w), C3);
    i += 16;
  }
  den += den2;
  A0 = __hadd2(A0, C0); A1 = __hadd2(A1, C1);
  A2 = __hadd2(A2, C2); A3 = __hadd2(A3, C3);
#pragma unroll
  for (int off = 8; off < 64; off <<= 1) {
    den += __shfl_xor(den, off);
    A0 = __hadd2(A0, shfl_h2(A0, off));
    A1 = __hadd2(A1, shfl_h2(A1, off));
    A2 = __hadd2(A2, shfl_h2(A2, off));
    A3 = __hadd2(A3, shfl_h2(A3, off));
  }
  if (lane < 8) {
    float inv = active ? (1.f / den) : 0.f;
    float4 b0 = *reinterpret_cast<const float4*>(bg + 8 * q);
    float4 b1 = *reinterpret_cast<const float4*>(bg + 8 * q + 4);
    float2 f0 = __half22float2(A0), f1 = __half22float2(A1);
    float2 f2 = __half22float2(A2), f3 = __half22float2(A3);
    int c0 = 8 * q;
    pacc[wid][c0 + 0] = active ? fmaxf(fmaf(f0.x, inv, b0.x), 0.f) : 0.f;
    pacc[wid][c0 + 1] = active ? fmaxf(fmaf(f0.y, inv, b0.y), 0.f) : 0.f;
    pacc[wid][c0 + 2] = active ? fmaxf(fmaf(f1.x, inv, b0.z), 0.f) : 0.f;
    pacc[wid][c0 + 3] = active ? fmaxf(fmaf(f1.y, inv, b0.w), 0.f) : 0.f;
    pacc[wid][c0 + 4] = active ? fmaxf(fmaf(f2.x, inv, b1.x), 0.f) : 0.f;
    pacc[wid][c0 + 5] = active ? fmaxf(fmaf(f2.y, inv, b1.y), 0.f) : 0.f;
    pacc[wid][c0 + 6] = active ? fmaxf(fmaf(f3.x, inv, b1.z), 0.f) : 0.f;
    pacc[wid][c0 + 7] = active ? fmaxf(fmaf(f3.y, inv, b1.w), 0.f) : 0.f;
  }
  __syncthreads();
  if (threadIdx.x < 64) {
    int t = threadIdx.x;
    partial1[(size_t)blockIdx.x * 64 + t] =
        pacc[0][t] + pacc[1][t] + pacc[2][t] + pacc[3][t];
  }
}

// ---------------- pooling + classifier ----------------

#define PBLK 512

__global__ __launch_bounds__(256) void pool_partial(const float* __restrict__ P1,
                                                    double* __restrict__ partial2,
                                                    unsigned total) {
  unsigned tid = blockIdx.x * 256u + threadIdx.x;
  unsigned stride = PBLK * 256u;
  double a = 0.0;
  for (unsigned i = tid; i < total; i += stride) a += (double)P1[i];
  __shared__ double red[256];
  red[threadIdx.x] = a;
  __syncthreads();
  if (threadIdx.x < 64) {
    int t = threadIdx.x;
    double s = red[t] + red[t + 64] + red[t + 128] + red[t + 192];
    partial2[(size_t)blockIdx.x * 64 + t] = s;
  }
}

__global__ __launch_bounds__(64) void final_kernel(const double* __restrict__ partial, int nblocks,
                                                   const float* __restrict__ Wc1,
                                                   const float* __restrict__ bc1,
                                                   const float* __restrict__ Wc2,
                                                   const float* __restrict__ bc2,
                                                   float* __restrict__ out, int n) {
  __shared__ float pooled[64];
  __shared__ float z[32];
  int t = threadIdx.x;
  double s = 0.0;
#pragma unroll 4
  for (int b = 0; b < nblocks; ++b) s += partial[(size_t)b * 64 + t];
  pooled[t] = (float)(s / (double)n);
  __syncthreads();
  if (t < 32) {
    double a = 0.0;
    for (int k = 0; k < 64; ++k) a += (double)pooled[k] * (double)Wc1[k * 32 + t];
    z[t] = fmaxf((float)a + bc1[t], 0.f);
  }
  __syncthreads();
  if (t < 2) {
    double a = 0.0;
    for (int j = 0; j < 32; ++j) a += (double)z[j] * (double)Wc2[j * 2 + t];
    out[t] = (float)a + bc2[t];
  }
}

// ---------------- launch ----------------

extern "C" void kernel_launch(void* const* d_in, const int* in_sizes, int n_in,
                              void* d_out, int out_size, void* d_ws, size_t ws_size,
                              hipStream_t stream) {
  const float* x   = (const float*)d_in[0];
  const int* eidx  = (const int*)d_in[1];
  const float* W1  = (const float*)d_in[2];
  const float* b1  = (const float*)d_in[3];
  const float* W2  = (const float*)d_in[4];
  const float* b2  = (const float*)d_in[5];
  const float* W3  = (const float*)d_in[6];
  const float* b3  = (const float*)d_in[7];
  const float* Wg  = (const float*)d_in[8];
  const float* att_src = (const float*)d_in[9];
  const float* att_dst = (const float*)d_in[10];
  const float* bg  = (const float*)d_in[11];
  const float* Wc1 = (const float*)d_in[12];
  const float* bc1 = (const float*)d_in[13];
  const float* Wc2 = (const float*)d_in[14];
  const float* bc2 = (const float*)d_in[15];

  const int n = in_sizes[0] / 64;   // 100000
  const int e = in_sizes[1] / 2;    // 1200000
  const int* src = eidx;
  const int* dst = eidx + e;

  char* ws = (char*)d_ws;
  size_t off = 0;
  auto alloc = [&](size_t bytes) {
    void* p = ws + off;
    off += (bytes + 255) & ~(size_t)255;
    return p;
  };
  const int nbuckets = (n + 255) >> 8;
  const int nblk4 = (n + 3) / 4;
  int*      cnt        = (int*)alloc((size_t)n * 4);
  int*      row_start  = (int*)alloc(((size_t)n + 1) * 4);
  unsigned* stream_b   = (unsigned*)alloc((size_t)e * 4);
  int*      csr_src    = (int*)alloc((size_t)e * 4);
  int*      bcnt       = (int*)alloc(NBK * 4);
  int*      bucket_base = (int*)alloc((NBK + 1) * 4);
  int*      gcursor    = (int*)alloc(NBK * 4);
  unsigned short* bufT = (unsigned short*)alloc((size_t)n * 64 * 2);  // fp16 messages
  unsigned short* bufF = (unsigned short*)alloc((size_t)n * 64 * 2);  // fp16 activations
  float*    a_s        = (float*)alloc((size_t)n * 4 * 4);
  float*    a_d        = (float*)alloc((size_t)n * 4 * 4);
  float*    partial1   = (float*)alloc((size_t)nblk4 * 64 * 4);
  double*   partial2   = (double*)alloc((size_t)PBLK * 64 * 8);

  hipMemsetAsync(bcnt, 0, NBK * 4, stream);

  int g64 = (n + 31) / 32;    // gemm2x4 OUT=64: 32 nodes/block
  int g32 = (n + 63) / 64;    // gemm2x4 OUT=32: 64 nodes/block
  int p1blk = (e + 256 * P1E - 1) / (256 * P1E);

  // graph build; gemm1 (scale-free) fused into the histogram dispatch
  hist_gemm1<<<p1blk + g64, 256, 0, stream>>>(dst, bcnt, e, p1blk, x, W1, bufT, n);
  bucket_scan<<<1, 512, 0, stream>>>(bcnt, bucket_base, gcursor, nbuckets, e);
  bin_pass1<<<p1blk, 256, 0, stream>>>(src, dst, gcursor, stream_b, e);
  bin_pass2<<<nbuckets, 256, 0, stream>>>(stream_b, bucket_base, row_start, cnt,
                                          csr_src, n, e);

  // GCN layer 1 (per-edge dinv; pre-scaled output)
  gcn_agg<64, true, true><<<nblk4, 256, 0, stream>>>(bufT, row_start, csr_src, cnt, b1, bufF, n);
  // GCN layer 2
  gemm2x4<64, 64, false><<<g64, 256, 0, stream>>>(bufF, W2, nullptr, nullptr,
                                                  bufT, nullptr, nullptr, n);
  gcn_agg<64, false, true><<<nblk4, 256, 0, stream>>>(bufT, row_start, csr_src, cnt, b2, bufF, n);
  // GCN layer 3 -> 32 channels (plain output for GAT)
  gemm2x4<64, 32, false><<<g32, 256, 0, stream>>>(bufF, W3, nullptr, nullptr,
                                                  bufT, nullptr, nullptr, n);
  gcn_agg<32, false, false><<<nblk4, 256, 0, stream>>>(bufT, row_start, csr_src, cnt, b3, bufF, n);
  // GAT projection + fused a_s/a_d
  gemm2x4<32, 64, true><<<g64, 256, 0, stream>>>(bufF, Wg, att_src, att_dst,
                                                 bufT, a_s, a_d, n);
  // GAT aggregate with fused mean-pool partials
  gat_agg<<<nblk4, 256, 0, stream>>>(bufT, a_s, a_d, row_start, csr_src, bg, partial1, n);
  // pool + MLP
  pool_partial<<<PBLK, 256, 0, stream>>>(partial1, partial2, (unsigned)nblk4 * 64u);
  final_kernel<<<1, 64, 0, stream>>>(partial2, PBLK, Wc1, bc1, Wc2, bc2, (float*)d_out, n);
}